// Round 1
// baseline (477.930 us; speedup 1.0000x reference)
//
#include <hip/hip_runtime.h>
#include <cstdint>
#include <cstddef>

// Problem constants (fixed by the reference generator)
#define DD 64           // feature dim D == A
#define N_RELTAB 401    // rel_emb rows
#define N_QR 8          // batchsize B
#define T_ROWS (N_RELTAB + N_QR)        // 409 rows: comb[0..400], hqr[401..408]
#define T_U16_STRIDE 66                 // u16 elements per row (64 + 2 pad, even)
#define T_U32_STRIDE 33                 // u32 pairs per row
#define T_U32_TOTAL (T_ROWS * T_U32_STRIDE)   // 13497 u32 = 53,988 B (< 64 KB static LDS)

__device__ __forceinline__ uint16_t f2bf(float f) {
    uint32_t u = __float_as_uint(f);
    u += 0x7fffu + ((u >> 16) & 1u);     // RNE
    return (uint16_t)(u >> 16);
}
__device__ __forceinline__ float bflo(uint32_t u) { return __uint_as_float(u << 16); }
__device__ __forceinline__ float bfhi(uint32_t u) { return __uint_as_float(u & 0xffff0000u); }

// K0: T[r] = Wr . rel_emb[r]        (r < 401)
//     T[401+k] = Wqr . rel_emb[q_rel[k]] + Wqr_b   (k < 8)
// stored bf16, row stride 66 u16.
__global__ __launch_bounds__(64) void build_T(
    const float* __restrict__ rel_emb, const float* __restrict__ Wr,
    const float* __restrict__ Wqr_w, const float* __restrict__ Wqr_b,
    const int* __restrict__ q_rel, uint16_t* __restrict__ T)
{
    int r = blockIdx.x, a = threadIdx.x;
    const float* w;
    const float* src;
    float acc;
    if (r < N_RELTAB) { w = Wr + a * DD; src = rel_emb + r * DD; acc = 0.f; }
    else {
        int k = r - N_RELTAB;
        w = Wqr_w + a * DD;
        src = rel_emb + q_rel[k] * DD;   // q_rel load is block-uniform
        acc = Wqr_b[a];
    }
#pragma unroll
    for (int d = 0; d < DD; ++d) acc = fmaf(src[d], w[d], acc);
    T[r * T_U16_STRIDE + a] = f2bf(acc);
}

// Row-per-lane matvec: out[n][a] = sum_d in[n][d] * W[a][d].
// W indices are wave-uniform -> s_load (SGPR operand), row held in VGPRs.
__global__ __launch_bounds__(256) void rowmat(
    const float* __restrict__ in, const float* __restrict__ W,
    float* __restrict__ out, int nrows)
{
    int n = blockIdx.x * 256 + threadIdx.x;
    if (n >= nrows) return;
    float row[DD];
    const float4* rp = (const float4*)(in + ((size_t)n << 6));
#pragma unroll
    for (int j = 0; j < DD / 4; ++j) {
        float4 v = rp[j];
        row[4*j+0] = v.x; row[4*j+1] = v.y; row[4*j+2] = v.z; row[4*j+3] = v.w;
    }
    float4* op = (float4*)(out + ((size_t)n << 6));
    for (int a0 = 0; a0 < DD; a0 += 4) {
        const float* w0 = W + a0 * DD;
        float s0 = 0.f, s1 = 0.f, s2 = 0.f, s3 = 0.f;
#pragma unroll
        for (int d = 0; d < DD; ++d) {
            float r = row[d];
            s0 = fmaf(w0[d],           r, s0);
            s1 = fmaf(w0[DD + d],      r, s1);
            s2 = fmaf(w0[2 * DD + d],  r, s2);
            s3 = fmaf(w0[3 * DD + d],  r, s3);
        }
        float4 o; o.x = s0; o.y = s1; o.z = s2; o.w = s3;
        op[a0 >> 2] = o;
    }
}

// K2a: per-edge alpha. Edge-per-lane; comb/hqr from LDS (bf16 pairs), X row gathered
// as 16x dwordx4 from global (L2/L3 resident).
__global__ __launch_bounds__(1024, 1) void alpha_kernel(
    const int* __restrict__ edges, const float* __restrict__ X,
    const uint32_t* __restrict__ Tg, const float* __restrict__ walpha_w,
    const float* __restrict__ walpha_b, float* __restrict__ alpha, int n_edge)
{
    __shared__ uint32_t sT[T_U32_TOTAL];
    for (int i = threadIdx.x; i < T_U32_TOTAL; i += 1024) sT[i] = Tg[i];
    __syncthreads();
    const float wb = walpha_b[0];
    for (int e = blockIdx.x * 1024 + threadIdx.x; e < n_edge; e += gridDim.x * 1024) {
        const int2* ep = (const int2*)(edges + 6 * e);   // 24 B row, 8-aligned
        int ridx = ep[0].x;          // col 0
        int rel  = ep[1].x;          // col 2
        int sub  = ep[2].x;          // col 4
        const float4* xp = (const float4*)(X + ((size_t)sub << 6));
        int cb = rel * T_U32_STRIDE;
        int qb = (N_RELTAB + ridx) * T_U32_STRIDE;
        float acc = 0.f;
#pragma unroll
        for (int j = 0; j < 16; ++j) {
            float4 x4 = xp[j];
            uint32_t c0 = sT[cb + 2 * j], c1 = sT[cb + 2 * j + 1];
            uint32_t q0 = sT[qb + 2 * j], q1 = sT[qb + 2 * j + 1];
            float p0 = x4.x + bflo(c0) + bflo(q0);
            float p1 = x4.y + bfhi(c0) + bfhi(q0);
            float p2 = x4.z + bflo(c1) + bflo(q1);
            float p3 = x4.w + bfhi(c1) + bfhi(q1);
            acc = fmaf(fmaxf(p0, 0.f), walpha_w[4 * j + 0], acc);
            acc = fmaf(fmaxf(p1, 0.f), walpha_w[4 * j + 1], acc);
            acc = fmaf(fmaxf(p2, 0.f), walpha_w[4 * j + 2], acc);
            acc = fmaf(fmaxf(p3, 0.f), walpha_w[4 * j + 3], acc);
        }
        alpha[e] = 1.f / (1.f + __expf(-(acc + wb)));
    }
}

// K2b: message scatter. Edge-per-wave (lane = feature) so atomics per edge hit
// 4 contiguous cache lines; hidden/rel_emb row reads coalesced. 4-edge unroll for MLP.
__global__ __launch_bounds__(256) void scatter_kernel(
    const int* __restrict__ edges, const float* __restrict__ hidden,
    const float* __restrict__ rel_emb, const float* __restrict__ alpha,
    float* __restrict__ agg, int n_edge)
{
    const int lane = threadIdx.x & 63;
    const int gw = (int)((blockIdx.x * blockDim.x + threadIdx.x) >> 6);
    const int nw = (int)((gridDim.x * blockDim.x) >> 6);
    for (int e0 = gw * 4; e0 < n_edge; e0 += nw * 4) {
#pragma unroll
        for (int k = 0; k < 4; ++k) {
            int e = e0 + k;
            if (e < n_edge) {               // wave-uniform guard
                int rel = edges[6 * e + 2];
                int sub = edges[6 * e + 4];
                int obj = edges[6 * e + 5];
                float al = alpha[e];
                float h = hidden[((size_t)sub << 6) + lane];
                float r = rel_emb[(rel << 6) + lane];
                atomicAdd(&agg[((size_t)obj << 6) + lane], al * (h + r));
            }
        }
    }
}

extern "C" void kernel_launch(void* const* d_in, const int* in_sizes, int n_in,
                              void* d_out, int out_size, void* d_ws, size_t ws_size,
                              hipStream_t stream)
{
    const int*   q_rel    = (const int*)d_in[1];
    const float* hidden   = (const float*)d_in[2];
    const int*   edges    = (const int*)d_in[3];
    const float* rel_emb  = (const float*)d_in[7];
    const float* Ws       = (const float*)d_in[8];
    const float* Wr       = (const float*)d_in[9];
    const float* Wqr_w    = (const float*)d_in[10];
    const float* Wqr_b    = (const float*)d_in[11];
    const float* walpha_w = (const float*)d_in[12];
    const float* walpha_b = (const float*)d_in[13];
    const float* Wh       = (const float*)d_in[14];
    float* out = (float*)d_out;

    const int n_node = in_sizes[2] / DD;   // 100000
    const int n_edge = in_sizes[3] / 6;    // 1000000

    // ws layout (floats): X[n_node*64] | agg[n_node*64] | alpha[n_edge] | T (u16)
    float* ws    = (float*)d_ws;
    float* X     = ws;
    float* agg   = X + (size_t)n_node * DD;
    float* alpha = agg + (size_t)n_node * DD;
    uint16_t* T  = (uint16_t*)(alpha + n_edge);

    build_T<<<T_ROWS, 64, 0, stream>>>(rel_emb, Wr, Wqr_w, Wqr_b, q_rel, T);
    rowmat<<<(n_node + 255) / 256, 256, 0, stream>>>(hidden, Ws, X, n_node);
    hipMemsetAsync(agg, 0, (size_t)n_node * DD * sizeof(float), stream);
    alpha_kernel<<<512, 1024, 0, stream>>>(edges, X, (const uint32_t*)T,
                                           walpha_w, walpha_b, alpha, n_edge);
    scatter_kernel<<<2048, 256, 0, stream>>>(edges, hidden, rel_emb, alpha, agg, n_edge);
    rowmat<<<(n_node + 255) / 256, 256, 0, stream>>>(agg, Wh, out, n_node);
}

// Round 2
// 455.392 us; speedup vs baseline: 1.0495x; 1.0495x over previous
//
#include <hip/hip_runtime.h>
#include <cstdint>
#include <cstddef>

// Problem constants (fixed by the reference generator)
#define DD 64           // feature dim D == A
#define N_RELTAB 401    // rel_emb rows
#define N_QR 8          // batchsize B
#define T_ROWS (N_RELTAB + N_QR)        // 409 rows: comb[0..400], hqr[401..408]
#define T_U16_STRIDE 66                 // u16 elements per row

__device__ __forceinline__ uint16_t f2bf(float f) {
    uint32_t u = __float_as_uint(f);
    u += 0x7fffu + ((u >> 16) & 1u);     // RNE
    return (uint16_t)(u >> 16);
}
__device__ __forceinline__ float bf2f(uint16_t u) {
    return __uint_as_float(((uint32_t)u) << 16);
}

// K0: T[r] = Wr . rel_emb[r]                      (r < 401)
//     T[401+k] = Wqr . rel_emb[q_rel[k]] + Wqr_b  (k < 8)
__global__ __launch_bounds__(64) void build_T(
    const float* __restrict__ rel_emb, const float* __restrict__ Wr,
    const float* __restrict__ Wqr_w, const float* __restrict__ Wqr_b,
    const int* __restrict__ q_rel, uint16_t* __restrict__ T)
{
    int r = blockIdx.x, a = threadIdx.x;
    const float* w;
    const float* src;
    float acc;
    if (r < N_RELTAB) { w = Wr + a * DD; src = rel_emb + r * DD; acc = 0.f; }
    else {
        int k = r - N_RELTAB;
        w = Wqr_w + a * DD;
        src = rel_emb + q_rel[k] * DD;   // block-uniform
        acc = Wqr_b[a];
    }
#pragma unroll
    for (int d = 0; d < DD; ++d) acc = fmaf(src[d], w[d], acc);
    T[r * T_U16_STRIDE + a] = f2bf(acc);
}

// Row-per-lane matvec: out[n][a] = sum_d in[n][d] * W[a][d].
__global__ __launch_bounds__(256) void rowmat(
    const float* __restrict__ in, const float* __restrict__ W,
    float* __restrict__ out, int nrows)
{
    int n = blockIdx.x * 256 + threadIdx.x;
    if (n >= nrows) return;
    float row[DD];
    const float4* rp = (const float4*)(in + ((size_t)n << 6));
#pragma unroll
    for (int j = 0; j < DD / 4; ++j) {
        float4 v = rp[j];
        row[4*j+0] = v.x; row[4*j+1] = v.y; row[4*j+2] = v.z; row[4*j+3] = v.w;
    }
    float4* op = (float4*)(out + ((size_t)n << 6));
    for (int a0 = 0; a0 < DD; a0 += 4) {
        const float* w0 = W + a0 * DD;
        float s0 = 0.f, s1 = 0.f, s2 = 0.f, s3 = 0.f;
#pragma unroll
        for (int d = 0; d < DD; ++d) {
            float r = row[d];
            s0 = fmaf(w0[d],          r, s0);
            s1 = fmaf(w0[DD + d],     r, s1);
            s2 = fmaf(w0[2 * DD + d], r, s2);
            s3 = fmaf(w0[3 * DD + d], r, s3);
        }
        float4 o; o.x = s0; o.y = s1; o.z = s2; o.w = s3;
        op[a0 >> 2] = o;
    }
}

// K1: histogram of obj
__global__ __launch_bounds__(256) void hist_kernel(
    const int* __restrict__ edges, int* __restrict__ counts, int n_edge)
{
    int e = blockIdx.x * 256 + threadIdx.x;
    if (e < n_edge) atomicAdd(&counts[edges[6 * e + 5]], 1);
}

// K2: per-chunk exclusive scan (chunk = 1024), writes block-local excl + block sums
__global__ __launch_bounds__(1024) void scan1(
    const int* __restrict__ counts, int* __restrict__ offsets,
    int* __restrict__ bsums, int n)
{
    __shared__ int wsum[16];
    int t = threadIdx.x, i = blockIdx.x * 1024 + t;
    int lane = t & 63, wid = t >> 6;
    int c = (i < n) ? counts[i] : 0;
    int v = c;
#pragma unroll
    for (int d = 1; d < 64; d <<= 1) { int u = __shfl_up(v, d); if (lane >= d) v += u; }
    if (lane == 63) wsum[wid] = v;
    __syncthreads();
    if (wid == 0) {
        int s = (lane < 16) ? wsum[lane] : 0;
#pragma unroll
        for (int d = 1; d < 16; d <<= 1) { int u = __shfl_up(s, d); if (lane >= d) s += u; }
        if (lane < 16) wsum[lane] = s;
    }
    __syncthreads();
    int woff = (wid == 0) ? 0 : wsum[wid - 1];
    if (i < n) offsets[i] = woff + v - c;
    if (t == 1023) bsums[blockIdx.x] = wsum[15];
}

// K3: serial scan of block sums (nb ~ 98)
__global__ void scan2(const int* __restrict__ bsums, int* __restrict__ boffs, int nb)
{
    if (threadIdx.x == 0 && blockIdx.x == 0) {
        int s = 0;
        for (int i = 0; i < nb; ++i) { boffs[i] = s; s += bsums[i]; }
    }
}

// K4: add block offsets; also init cursor = offsets
__global__ __launch_bounds__(1024) void scan3(
    int* __restrict__ offsets, int* __restrict__ cursor,
    const int* __restrict__ boffs, int n)
{
    int i = blockIdx.x * 1024 + threadIdx.x;
    if (i < n) {
        int v = offsets[i] + boffs[blockIdx.x];
        offsets[i] = v;
        cursor[i] = v;
    }
}

// K5: counting-sort edges by obj; payload packs sub(17b) | rel(9b) | ridx(3b)
__global__ __launch_bounds__(256) void build_sorted(
    const int* __restrict__ edges, int* __restrict__ cursor,
    uint32_t* __restrict__ sorted, int n_edge)
{
    int e = blockIdx.x * 256 + threadIdx.x;
    if (e >= n_edge) return;
    const int2* ep = (const int2*)(edges + 6 * e);
    int ridx = ep[0].x;
    int rel  = ep[1].x;
    int2 so  = ep[2];        // sub, obj
    int pos = atomicAdd(&cursor[so.y], 1);
    sorted[pos] = (uint32_t)so.x | ((uint32_t)rel << 17) | ((uint32_t)ridx << 26);
}

// K6: gather-aggregate. One wave per node, lane = feature.
// alpha computed inline via cross-lane reduce; message accumulated in registers.
__global__ __launch_bounds__(256) void aggregate(
    const uint32_t* __restrict__ sorted, const int* __restrict__ offsets,
    const int* __restrict__ counts, const float* __restrict__ X,
    const float* __restrict__ hidden, const uint16_t* __restrict__ T,
    const float* __restrict__ rel_emb, const float* __restrict__ walpha_w,
    const float* __restrict__ walpha_b, float* __restrict__ agg, int n_node)
{
    __shared__ float sQ[N_QR * DD];      // hqr rows, f32
    int tid = threadIdx.x;
    int lane = tid & 63, wid = tid >> 6;
    for (int i = tid; i < N_QR * DD; i += 256)
        sQ[i] = bf2f(T[(N_RELTAB + (i >> 6)) * T_U16_STRIDE + (i & 63)]);
    __syncthreads();

    float wa = walpha_w[lane];
    float wb = walpha_b[0];

    int n = blockIdx.x * 4 + wid;
    if (n >= n_node) return;
    int start = offsets[n];
    int cnt   = counts[n];
    float acc = 0.f;
    for (int i = 0; i < cnt; ++i) {
        uint32_t p = sorted[start + i];
        int sub  = (int)(p & 0x1FFFFu);
        int rel  = (int)((p >> 17) & 0x1FFu);
        int ridx = (int)(p >> 26);
        float x = X[((size_t)sub << 6) + lane];
        float h = hidden[((size_t)sub << 6) + lane];
        float c = bf2f(T[rel * T_U16_STRIDE + lane]);
        float q = sQ[(ridx << 6) + lane];
        float r = rel_emb[(rel << 6) + lane];
        float t = fmaxf(x + c + q, 0.f) * wa;
#pragma unroll
        for (int off = 32; off; off >>= 1) t += __shfl_xor(t, off);
        float alpha = 1.f / (1.f + __expf(-(t + wb)));
        acc = fmaf(alpha, h + r, acc);
    }
    agg[((size_t)n << 6) + lane] = acc;
}

extern "C" void kernel_launch(void* const* d_in, const int* in_sizes, int n_in,
                              void* d_out, int out_size, void* d_ws, size_t ws_size,
                              hipStream_t stream)
{
    const int*   q_rel    = (const int*)d_in[1];
    const float* hidden   = (const float*)d_in[2];
    const int*   edges    = (const int*)d_in[3];
    const float* rel_emb  = (const float*)d_in[7];
    const float* Ws       = (const float*)d_in[8];
    const float* Wr       = (const float*)d_in[9];
    const float* Wqr_w    = (const float*)d_in[10];
    const float* Wqr_b    = (const float*)d_in[11];
    const float* walpha_w = (const float*)d_in[12];
    const float* walpha_b = (const float*)d_in[13];
    const float* Wh       = (const float*)d_in[14];
    float* out = (float*)d_out;

    const int n_node = in_sizes[2] / DD;   // 100000
    const int n_edge = in_sizes[3] / 6;    // 1000000
    const int NB = (n_node + 1023) / 1024; // scan chunks (98)

    // ws layout (bytes, 64B-aligned segments):
    //   X[n_node*64]f32 | agg[n_node*64]f32 | sorted[n_edge]u32 |
    //   counts[n_node] | offsets[n_node] | cursor[n_node] |
    //   bsums[1024] | boffs[1024] | T[409*66]u16
    char* w = (char*)d_ws;
    float*    X       = (float*)w;               w += (size_t)n_node * DD * 4;
    float*    agg     = (float*)w;               w += (size_t)n_node * DD * 4;
    uint32_t* sorted  = (uint32_t*)w;            w += (size_t)n_edge * 4;
    int*      counts  = (int*)w;                 w += (size_t)n_node * 4;
    int*      offsets = (int*)w;                 w += (size_t)n_node * 4;
    int*      cursor  = (int*)w;                 w += (size_t)n_node * 4;
    int*      bsums   = (int*)w;                 w += 4096;
    int*      boffs   = (int*)w;                 w += 4096;
    uint16_t* T       = (uint16_t*)w;

    build_T<<<T_ROWS, 64, 0, stream>>>(rel_emb, Wr, Wqr_w, Wqr_b, q_rel, T);
    rowmat<<<(n_node + 255) / 256, 256, 0, stream>>>(hidden, Ws, X, n_node);
    hipMemsetAsync(counts, 0, (size_t)n_node * 4, stream);
    hist_kernel<<<(n_edge + 255) / 256, 256, 0, stream>>>(edges, counts, n_edge);
    scan1<<<NB, 1024, 0, stream>>>(counts, offsets, bsums, n_node);
    scan2<<<1, 64, 0, stream>>>(bsums, boffs, NB);
    scan3<<<NB, 1024, 0, stream>>>(offsets, cursor, boffs, n_node);
    build_sorted<<<(n_edge + 255) / 256, 256, 0, stream>>>(edges, cursor, sorted, n_edge);
    aggregate<<<(n_node + 3) / 4, 256, 0, stream>>>(sorted, offsets, counts, X, hidden,
                                                    T, rel_emb, walpha_w, walpha_b,
                                                    agg, n_node);
    rowmat<<<(n_node + 255) / 256, 256, 0, stream>>>(agg, Wh, out, n_node);
}